// Round 4
// baseline (138.126 us; speedup 1.0000x reference)
//
#include <hip/hip_runtime.h>

constexpr int Bb = 8;
constexpr int Nn = 2048;
constexpr int Cc = 64;
constexpr int CAPS = 192;

typedef __attribute__((ext_vector_type(4))) float f32x4;
typedef __attribute__((ext_vector_type(8))) short bf16x8;

__device__ inline unsigned short f2bf(float f){
  unsigned u = __builtin_bit_cast(unsigned, f);
  unsigned r = (u + 0x7FFFu + ((u>>16)&1u)) >> 16;
  return (unsigned short)r;
}
__device__ inline float bf2f(unsigned short h){
  unsigned u = ((unsigned)h)<<16; return __builtin_bit_cast(float,u);
}

// ===== mega pre-kernel: prep(QK hi/lo + xt + xsum partials) | extract | WvT | zero =====
__global__ __launch_bounds__(256) void mega_k(
    const float* __restrict__ x, const float* __restrict__ A,
    const float* __restrict__ Wq, const float* __restrict__ Wk,
    const float* __restrict__ Tw, const float* __restrict__ Wv,
    unsigned short* __restrict__ Qhi, unsigned short* __restrict__ Qlo,
    unsigned short* __restrict__ Khi, unsigned short* __restrict__ Klo,
    float* __restrict__ xt, float* __restrict__ Xp,
    float* __restrict__ r_, float* __restrict__ diagA, int* __restrict__ cnt,
    int* __restrict__ idx, float* __restrict__ val,
    float* __restrict__ WvT, char* __restrict__ zerobase){
  __shared__ __attribute__((aligned(16))) char smem[65792];
  int blk = blockIdx.x; int t = threadIdx.x;

  if(blk < 256){
    // ---------------- prep ----------------
    float* wql = (float*)smem;           // 4096 f
    float* wkl = wql + 4096;
    float* twl = wkl + 4096;
    float (*xr)[64] = (float(*)[64])(twl + 4096); // [64][64]
    float* xsl = (float*)(xr + 64);      // 64 f
    #pragma unroll
    for(int i=0;i<4;i++){
      *(f32x4*)&wql[i*1024+t*4] = *(const f32x4*)&Wq[i*1024+t*4];
      *(f32x4*)&wkl[i*1024+t*4] = *(const f32x4*)&Wk[i*1024+t*4];
      *(f32x4*)&twl[i*1024+t*4] = *(const f32x4*)&Tw[i*1024+t*4];
    }
    if(t<64) xsl[t]=0.f;
    long long row0 = (long long)blk*64;
    int r = t>>4, q = t&15, c0 = q*4;
    #pragma unroll
    for(int i=0;i<4;i++){
      int row = i*16 + r;
      *(f32x4*)&xr[row][c0] = *(const f32x4*)&x[(row0+row)*Cc + c0];
    }
    __syncthreads();
    f32x4 aq[4], ak[4], at4[4];
    #pragma unroll
    for(int g=0;g<4;g++){ aq[g]=(f32x4){0,0,0,0}; ak[g]=(f32x4){0,0,0,0}; at4[g]=(f32x4){0,0,0,0}; }
    for(int kk=0;kk<64;kk++){
      f32x4 wq4 = *(const f32x4*)&wql[kk*64+c0];
      f32x4 wk4 = *(const f32x4*)&wkl[kk*64+c0];
      f32x4 wt4 = *(const f32x4*)&twl[kk*64+c0];
      #pragma unroll
      for(int g=0;g<4;g++){
        float xv = xr[g*16+r][kk];
        aq[g] += xv*wq4; ak[g] += xv*wk4; at4[g] += xv*wt4;
      }
    }
    float xsp[4] = {0.f,0.f,0.f,0.f};
    #pragma unroll
    for(int g=0;g<4;g++){
      #pragma unroll
      for(int d=0;d<4;d++) xsp[d] += xr[g*16+r][c0+d];
      long long g2 = (row0 + g*16 + r)*Cc + c0;
      unsigned long long hq=0,lq=0,hk=0,lk=0;
      #pragma unroll
      for(int d=0;d<4;d++){
        float v = aq[g][d];
        unsigned short h = f2bf(v); unsigned short lo2 = f2bf(v - bf2f(h));
        hq |= (unsigned long long)h << (16*d); lq |= (unsigned long long)lo2 << (16*d);
        v = ak[g][d];
        h = f2bf(v); lo2 = f2bf(v - bf2f(h));
        hk |= (unsigned long long)h << (16*d); lk |= (unsigned long long)lo2 << (16*d);
      }
      *(unsigned long long*)&Qhi[g2] = hq;
      *(unsigned long long*)&Qlo[g2] = lq;
      *(unsigned long long*)&Khi[g2] = hk;
      *(unsigned long long*)&Klo[g2] = lk;
      *(f32x4*)&xt[g2] = at4[g];
    }
    __syncthreads();
    #pragma unroll
    for(int d=0;d<4;d++) atomicAdd(&xsl[c0+d], xsp[d]);
    __syncthreads();
    if(t<64) Xp[blk*64+t] = xsl[t];
  } else if(blk < 768){
    // ---------------- extract ----------------
    int n = (blk-256)*4 + (t>>6); int l = t&63;
    const float* row = A + (size_t)n*Nn;
    float mn = 1e30f;
    for(int j=l;j<Nn;j+=64) mn = fminf(mn, row[j]);
    #pragma unroll
    for(int off=32;off>=1;off>>=1) mn = fminf(mn, __shfl_xor(mn,off));
    float thr = mn*1.3f;
    int bse=0;
    for(int j0=0;j0<Nn;j0+=64){
      float v = row[j0+l];
      bool f = v>thr;
      unsigned long long m = __ballot(f);
      int pos = __popcll(m & ((1ull<<l)-1ull));
      if(f && bse+pos<CAPS){ idx[n*CAPS+bse+pos]=j0+l; val[n*CAPS+bse+pos]=v-mn; }
      bse += __popcll(m);
    }
    if(l==0){ r_[n]=mn; diagA[n]=row[n]; cnt[n] = bse<CAPS? bse : CAPS; }
  } else if(blk < 800){
    // ---------------- WvT ----------------
    float (*tile)[65] = (float(*)[65])smem;
    int n0 = (blk-768)*64;
    for(int i=0;i<16;i++){
      int cc = i*4 + (t>>6); int nn2 = t&63;
      tile[cc][nn2] = Wv[(size_t)cc*Nn + n0 + nn2];
    }
    __syncthreads();
    for(int i=0;i<16;i++){
      int nn2 = i*4 + (t>>6); int cc = t&63;
      WvT[(size_t)(n0+nn2)*Cc + cc] = tile[cc][nn2];
    }
  } else {
    // ---------------- zero P+Z ----------------
    char* dst = zerobase + (size_t)(blk-800)*65536;
    uint4 zz = {0,0,0,0};
    #pragma unroll
    for(int i=0;i<16;i++) *(uint4*)(dst + ((size_t)i*256 + t)*16) = zz;
  }
}

// ---- GEMM1 (LDS-free): E[b][j][m] = bf16(exp(Q[b,j]·K[b,m])), col sums -> Z ----
__global__ __launch_bounds__(256) void gemm1_k(
    const unsigned short* __restrict__ Qhi, const unsigned short* __restrict__ Qlo,
    const unsigned short* __restrict__ Khi, const unsigned short* __restrict__ Klo,
    unsigned short* __restrict__ E, float* __restrict__ Z){
  __shared__ float colsum[128];
  int t = threadIdx.x;
  int b = blockIdx.z;
  int j0 = blockIdx.x*128, m0 = blockIdx.y*128;
  int w=t>>6, l=t&63;
  int wm=(w>>1)*64, wn=(w&1)*64;
  if(t<128) colsum[t]=0.f;
  __syncthreads();
  size_t bq = ((size_t)b*Nn + j0)*Cc;
  size_t bk = ((size_t)b*Nn + m0)*Cc;
  const unsigned short* qhB = Qhi + bq;
  const unsigned short* qlB = Qlo + bq;
  const unsigned short* khB = Khi + bk;
  const unsigned short* klB = Klo + bk;
  f32x4 acc[4][4];
  #pragma unroll
  for(int i=0;i<4;i++)
    #pragma unroll
    for(int j=0;j<4;j++) acc[i][j]=(f32x4){0.f,0.f,0.f,0.f};
  #pragma unroll
  for(int ks=0;ks<2;ks++){
    int co = ks*32 + (l>>4)*8;   // short offset within 64-short row
    bf16x8 ah[4],al2[4],bh[4],bl[4];
    #pragma unroll
    for(int i=0;i<4;i++){
      size_t ra = (size_t)(wm+i*16+(l&15))*Cc + co;
      ah[i]  = *(const bf16x8*)(qhB + ra);
      al2[i] = *(const bf16x8*)(qlB + ra);
      size_t rb = (size_t)(wn+i*16+(l&15))*Cc + co;
      bh[i]  = *(const bf16x8*)(khB + rb);
      bl[i]  = *(const bf16x8*)(klB + rb);
    }
    #pragma unroll
    for(int i=0;i<4;i++)
      #pragma unroll
      for(int j=0;j<4;j++){
        acc[i][j]=__builtin_amdgcn_mfma_f32_16x16x32_bf16(ah[i],bh[j],acc[i][j],0,0,0);
        acc[i][j]=__builtin_amdgcn_mfma_f32_16x16x32_bf16(al2[i],bh[j],acc[i][j],0,0,0);
        acc[i][j]=__builtin_amdgcn_mfma_f32_16x16x32_bf16(ah[i],bl[j],acc[i][j],0,0,0);
      }
  }
  unsigned short* Eb = E + ((size_t)b*Nn + j0)*Nn + m0;
  float cs[4] = {0.f,0.f,0.f,0.f};
  #pragma unroll
  for(int i=0;i<4;i++){
    int row = wm+i*16+(l>>4)*4;
    #pragma unroll
    for(int j=0;j<4;j++){
      int col = wn+j*16+(l&15);
      #pragma unroll
      for(int q=0;q<4;q++){
        unsigned short h = f2bf(__expf(acc[i][j][q]));
        Eb[(size_t)(row+q)*Nn + col] = h;
        cs[j] += bf2f(h);
      }
    }
  }
  #pragma unroll
  for(int j=0;j<4;j++)
    atomicAdd(&colsum[wn + j*16 + (l&15)], cs[j]);
  __syncthreads();
  if(t<128) atomicAdd(&Z[(size_t)b*Nn + m0 + t], colsum[t]);
}

// -- xzT (chunk-XOR pre-swizzled): phys chunk = (m>>3)^(c&7) within each row --
__global__ __launch_bounds__(256) void xzt_k(const float* __restrict__ x,
    const float* __restrict__ Z, unsigned short* __restrict__ xzT){
  __shared__ float tile[64][65];
  int b = blockIdx.y;
  int m0 = blockIdx.x*64; int t = threadIdx.x;
  for(int i=0;i<16;i++){
    int mm = i*4 + (t>>6); int cc = t&63;
    tile[mm][cc] = x[((size_t)b*Nn + m0+mm)*Cc + cc];
  }
  __syncthreads();
  for(int i=0;i<16;i++){
    int cc = i*4 + (t>>6); int mm = t&63;
    int mabs = m0 + mm;
    float iz = 1.0f/Z[(size_t)b*Nn + mabs];
    int cmp = (mabs>>3) ^ (cc&7);
    size_t pos = ((size_t)b*Cc + cc)*Nn + ((size_t)cmp<<3) + (mabs&7);
    xzT[pos] = f2bf(tile[mm][cc]*iz);
  }
}

// --- GEMM2: stream E (global->reg fragments), xb staged once, zero inner barriers ---
__global__ __launch_bounds__(256) void gemm2_k(const unsigned short* __restrict__ E,
    const unsigned short* __restrict__ xzT, float* __restrict__ P){
  __shared__ uint4 xb[4096]; // 64 KiB: [c=64][chunk=64 of 16B] (pre-swizzled)
  int t = threadIdx.x;
  int b = blockIdx.z;
  int j0 = blockIdx.x*128;
  int kc = blockIdx.y;
  // stage xz window: rows c=0..63, physical bytes [kc*1024, +1024) of each row
  {
    const uint4* src = (const uint4*)(xzT + (size_t)b*Cc*Nn) + kc*64;
    #pragma unroll
    for(int i=0;i<16;i++){
      int idx2 = i*256+t; int row = idx2>>6, col = idx2&63;
      xb[idx2] = src[(size_t)row*256 + col];
    }
  }
  __syncthreads();
  int w = t>>6, l = t&63;
  const unsigned short* Er0 = E + ((size_t)b*Nn + j0 + w*32      + (l&15))*Nn + kc*512 + (l>>4)*8;
  const unsigned short* Er1 = E + ((size_t)b*Nn + j0 + w*32 + 16 + (l&15))*Nn + kc*512 + (l>>4)*8;
  int cbase = (l&15)*64;       // c-row base in xb units (j adds 16*64)
  int sw = l&7;                // chunk XOR key (c&7 == l&7 for all j)
  int ch0 = (l>>4);            // chunk sub-index
  f32x4 acc[2][4];
  #pragma unroll
  for(int i=0;i<2;i++)
    #pragma unroll
    for(int j=0;j<4;j++) acc[i][j]=(f32x4){0.f,0.f,0.f,0.f};

  bf16x8 Aa0,Aa1,Ab0,Ab1,Ab2,Ab3;
  bf16x8 Ba0,Ba1,Bb0,Bb1,Bb2,Bb3;
#define LDF(P0,P1,Q0,Q1,Q2,Q3,st) { \
    int mo = (st)*32; int c4 = (st)*4 + ch0; \
    P0 = *(const bf16x8*)(Er0 + mo); \
    P1 = *(const bf16x8*)(Er1 + mo); \
    Q0 = *(bf16x8*)&xb[cbase        + (c4^sw)]; \
    Q1 = *(bf16x8*)&xb[cbase + 1024 + (c4^sw)]; \
    Q2 = *(bf16x8*)&xb[cbase + 2048 + (c4^sw)]; \
    Q3 = *(bf16x8*)&xb[cbase + 3072 + (c4^sw)]; }
#define MM(P0,P1,Q0,Q1,Q2,Q3) { \
    acc[0][0]=__builtin_amdgcn_mfma_f32_16x16x32_bf16(P0,Q0,acc[0][0],0,0,0); \
    acc[0][1]=__builtin_amdgcn_mfma_f32_16x16x32_bf16(P0,Q1,acc[0][1],0,0,0); \
    acc[0][2]=__builtin_amdgcn_mfma_f32_16x16x32_bf16(P0,Q2,acc[0][2],0,0,0); \
    acc[0][3]=__builtin_amdgcn_mfma_f32_16x16x32_bf16(P0,Q3,acc[0][3],0,0,0); \
    acc[1][0]=__builtin_amdgcn_mfma_f32_16x16x32_bf16(P1,Q0,acc[1][0],0,0,0); \
    acc[1][1]=__builtin_amdgcn_mfma_f32_16x16x32_bf16(P1,Q1,acc[1][1],0,0,0); \
    acc[1][2]=__builtin_amdgcn_mfma_f32_16x16x32_bf16(P1,Q2,acc[1][2],0,0,0); \
    acc[1][3]=__builtin_amdgcn_mfma_f32_16x16x32_bf16(P1,Q3,acc[1][3],0,0,0); }

  LDF(Aa0,Aa1,Ab0,Ab1,Ab2,Ab3, 0);
  #pragma unroll
  for(int s2=0; s2<16; s2+=2){
    if(s2+1<16) LDF(Ba0,Ba1,Bb0,Bb1,Bb2,Bb3, s2+1);
    MM(Aa0,Aa1,Ab0,Ab1,Ab2,Ab3);
    if(s2+2<16) LDF(Aa0,Aa1,Ab0,Ab1,Ab2,Ab3, s2+2);
    if(s2+1<16) MM(Ba0,Ba1,Bb0,Bb1,Bb2,Bb3);
  }
#undef LDF
#undef MM
  float* Pb = P + ((size_t)b*Nn + j0)*Cc;
  #pragma unroll
  for(int i=0;i<2;i++){
    int row = w*32 + i*16 + (l>>4)*4;
    #pragma unroll
    for(int j=0;j<4;j++){
      int col = j*16 + (l&15);
      #pragma unroll
      for(int q=0;q<4;q++)
        atomicAdd(&Pb[(size_t)(row+q)*Cc + col], acc[i][j][q]);
    }
  }
}

// ---------------- final: dy_diag + elementwise combine ----------------
__global__ __launch_bounds__(256) void final_k(const float* __restrict__ x,
    const float* __restrict__ xt, const float* __restrict__ P,
    const float* __restrict__ WvT, const float* __restrict__ Xp,
    const float* __restrict__ r_, const float* __restrict__ diagA,
    const int* __restrict__ cnt, const int* __restrict__ idx,
    const float* __restrict__ val, const float* __restrict__ tb,
    const float* __restrict__ alp, const float* __restrict__ bet,
    float* __restrict__ out){
  int t=threadIdx.x; int l=t&63;
  int bn = blockIdx.x*4 + (t>>6);
  int b = bn>>11, n = bn&2047;
  float wv = WvT[n*Cc+l];
  float xs = 0.f;
  const float* xpb = Xp + (size_t)b*32*Cc;
  #pragma unroll 8
  for(int p=0;p<32;p++) xs += xpb[p*Cc + l];
  float tacc = r_[n]*xs;
  int cn = cnt[n];
  const float* Pb = P + (size_t)b*Nn*Cc;
  const int* ix = idx + n*CAPS;
  const float* vl = val + n*CAPS;
  for(int k=0;k<cn;k++)
    tacc += vl[k] * Pb[(size_t)ix[k]*Cc + l];
  float d = wv*tacc;
  #pragma unroll
  for(int off=32;off>=1;off>>=1) d += __shfl_xor(d,off);
  size_t g = (size_t)bn*Cc + l;
  float o = alp[0]*diagA[n]*x[g] + bet[0]*(d*xt[g] + tb[l]);
  out[g] = fmaxf(o,0.f);
}

extern "C" void kernel_launch(void* const* d_in, const int* in_sizes, int n_in,
                              void* d_out, int out_size, void* d_ws, size_t ws_size,
                              hipStream_t stream){
  const float* x  = (const float*)d_in[0];
  const float* A  = (const float*)d_in[1];
  const float* Wq = (const float*)d_in[2];
  const float* Wk = (const float*)d_in[3];
  const float* Wv = (const float*)d_in[4];
  const float* Tw = (const float*)d_in[5];
  const float* tb = (const float*)d_in[6];
  const float* alp= (const float*)d_in[7];
  const float* bet= (const float*)d_in[8];
  float* out = (float*)d_out;

  char* base = (char*)d_ws; size_t off=0;
  auto al=[&](size_t sz)->void*{ void* q = base+off; off=(off+sz+255)&~(size_t)255; return q; };
  unsigned short* Qhi=(unsigned short*)al((size_t)Bb*Nn*Cc*2);
  unsigned short* Qlo=(unsigned short*)al((size_t)Bb*Nn*Cc*2);
  unsigned short* Khi=(unsigned short*)al((size_t)Bb*Nn*Cc*2);
  unsigned short* Klo=(unsigned short*)al((size_t)Bb*Nn*Cc*2);
  float* xt  =(float*)al((size_t)Bb*Nn*Cc*4);
  float* P   =(float*)al((size_t)Bb*Nn*Cc*4);   // zeroed by mega_k
  float* Z   =(float*)al((size_t)Bb*Nn*4);      // zeroed by mega_k (contiguous after P)
  float* Xp  =(float*)al((size_t)256*Cc*4);
  float* WvT =(float*)al((size_t)Nn*Cc*4);
  float* r_  =(float*)al((size_t)Nn*4);
  float* dgA =(float*)al((size_t)Nn*4);
  int*   cnt =(int*)al((size_t)Nn*4);
  int*   idx =(int*)al((size_t)Nn*CAPS*4);
  float* val =(float*)al((size_t)Nn*CAPS*4);
  unsigned short* xzT=(unsigned short*)al((size_t)Bb*Cc*Nn*2);
  unsigned short* E  =(unsigned short*)al((size_t)Bb*Nn*Nn*2);
  (void)ws_size;

  mega_k<<<865, 256, 0, stream>>>(x, A, Wq, Wk, Tw, Wv,
      Qhi, Qlo, Khi, Klo, xt, Xp, r_, dgA, cnt, idx, val, WvT, (char*)P);
  gemm1_k<<<dim3(16,16,Bb), 256, 0, stream>>>(Qhi,Qlo,Khi,Klo,E,Z);
  xzt_k<<<dim3(32,Bb), 256, 0, stream>>>(x,Z,xzT);
  gemm2_k<<<dim3(16,4,Bb), 256, 0, stream>>>(E,xzT,P);
  final_k<<<Bb*Nn/4, 256, 0, stream>>>(x,xt,P,WvT,Xp,r_,dgA,cnt,idx,val,tb,alp,bet,out);
}